// Round 11
// baseline (275.931 us; speedup 1.0000x reference)
//
#include <hip/hip_runtime.h>
#include <hip/hip_bf16.h>

#define N_IN    4096
#define N_OUT   4096
#define RANK    64
#define RES_RANK 4
#define RTOT    68      // RANK + RES_RANK
#define KPAD    96      // RTOT padded to 3 MFMA k-steps of 32
#define BATCH   8192
#define KSPLIT  16
#define KCHUNK  256     // N_IN / KSPLIT
#define SVSTR   264     // sV row stride in shorts (k=256 + 8 pad; 16B-aligned rows)

typedef short bf16x8 __attribute__((ext_vector_type(8)));   // MFMA A/B frag (4 VGPRs)
typedef float f32x4  __attribute__((ext_vector_type(4)));   // MFMA C/D frag

__device__ inline short f2bf(float f) {
    __hip_bfloat16 h = __float2bfloat16(f);
    return *reinterpret_cast<short*>(&h);
}

// ---------------------------------------------------------------------------
// Phase A (barrier-free K-loop):
//   t_part[ks][b][r] = sum_{k in chunk ks} x[k][b] * Vcat[k][r]
// A-operand (m=batch) comes STRAIGHT from global x (8 row-strided dwords per
// frag; 64-lane footprint = 4 full 128B lines, no overfetch, no LDS, no
// barriers). B-operand = Vcat^T staged once per block into LDS as [r][k] bf16.
// MFMA 16x16x32 bf16, verified C/D mapping col=lane&15, row=(lane>>4)*4+reg.
// ---------------------------------------------------------------------------
__global__ __launch_bounds__(256) void phaseA_kernel(
    const float* __restrict__ x,
    const float* __restrict__ V,
    const float* __restrict__ Vr,
    float* __restrict__ t_part)
{
    __shared__ __align__(16) unsigned short sV[80][SVSTR];  // [r][k], rows 68..79 zero
    const int tid  = threadIdx.x;
    const int lane = tid & 63;
    const int wv   = tid >> 6;
    const int ln15 = lane & 15;
    const int g    = lane >> 4;
    const int b0   = blockIdx.x * 128;
    const int ks   = blockIdx.y;
    const int k0   = ks * KCHUNK;

    // zero pad rows r = 68..79 (their MFMA results are masked on store anyway)
    for (int i = tid; i < 12 * (SVSTR / 2); i += 256) {
        int r = 68 + i / (SVSTR / 2), c = i % (SVSTR / 2);
        *(unsigned int*)&sV[r][c * 2] = 0u;
    }

    // stage Vcat^T: thread owns one k-row (k-local = tid, KCHUNK == 256 threads).
    // Scatter writes sV[r][tid]: per instr lanes span k -> banks 2-way (free).
    {
        const float* vrow = V + (size_t)(k0 + tid) * RANK;
#pragma unroll
        for (int c = 0; c < 16; ++c) {
            float4 v = *(const float4*)(vrow + c * 4);
            sV[c * 4 + 0][tid] = (unsigned short)f2bf(v.x);
            sV[c * 4 + 1][tid] = (unsigned short)f2bf(v.y);
            sV[c * 4 + 2][tid] = (unsigned short)f2bf(v.z);
            sV[c * 4 + 3][tid] = (unsigned short)f2bf(v.w);
        }
        float4 vr4 = *(const float4*)(Vr + (size_t)(k0 + tid) * RES_RANK);
        sV[64][tid] = (unsigned short)f2bf(vr4.x);
        sV[65][tid] = (unsigned short)f2bf(vr4.y);
        sV[66][tid] = (unsigned short)f2bf(vr4.z);
        sV[67][tid] = (unsigned short)f2bf(vr4.w);
    }
    __syncthreads();   // the ONLY barrier in this kernel

    f32x4 acc[2][5];
#pragma unroll
    for (int q = 0; q < 2; ++q)
#pragma unroll
        for (int nt = 0; nt < 5; ++nt)
            acc[q][nt] = (f32x4)0.0f;

#pragma unroll 2
    for (int kk = 0; kk < KCHUNK; kk += 32) {
        // ---- A frags: direct from global x (f32 -> bf16 in register) ----
        bf16x8 a[2];
#pragma unroll
        for (int q = 0; q < 2; ++q) {
            const float* xp = x + (size_t)(k0 + kk + g * 8) * BATCH
                            + b0 + (wv * 2 + q) * 16 + ln15;
            float f0 = xp[0 * BATCH], f1 = xp[1 * BATCH];
            float f2 = xp[2 * BATCH], f3 = xp[3 * BATCH];
            float f4 = xp[4 * BATCH], f5 = xp[5 * BATCH];
            float f6 = xp[6 * BATCH], f7 = xp[7 * BATCH];
            a[q][0] = f2bf(f0); a[q][1] = f2bf(f1);
            a[q][2] = f2bf(f2); a[q][3] = f2bf(f3);
            a[q][4] = f2bf(f4); a[q][5] = f2bf(f5);
            a[q][6] = f2bf(f6); a[q][7] = f2bf(f7);
        }
        // ---- B frags: aligned ds_read_b128 from sV ----
        bf16x8 bfr[5];
#pragma unroll
        for (int nt = 0; nt < 5; ++nt)
            bfr[nt] = *(const bf16x8*)&sV[nt * 16 + ln15][kk + g * 8];

#pragma unroll
        for (int q = 0; q < 2; ++q)
#pragma unroll
            for (int nt = 0; nt < 5; ++nt)
                acc[q][nt] = __builtin_amdgcn_mfma_f32_16x16x32_bf16(
                    a[q], bfr[nt], acc[q][nt], 0, 0, 0);
    }

    // ---- epilogue: t_part[ks][b][r], r < 68 only (nt=4 lanes ln15>=4 masked) ----
#pragma unroll
    for (int q = 0; q < 2; ++q)
#pragma unroll
        for (int nt = 0; nt < 5; ++nt)
#pragma unroll
            for (int r = 0; r < 4; ++r) {
                int b  = b0 + (wv * 2 + q) * 16 + g * 4 + r;  // row = (lane>>4)*4+reg
                int rr = nt * 16 + ln15;                       // col = lane&15
                if (rr < RTOT)
                    t_part[((size_t)ks * BATCH + b) * RTOT + rr] = acc[q][nt][r];
            }
}

// ---------------------------------------------------------------------------
// Reduce: t_bf16[b][rr] = bf16( sum_ks t_part[ks][b][rr] ) for rr<68, else 0.
// Flat 1 thread per (b, rr) over BATCH*KPAD; fully-coalesced bf16 writes.
// ---------------------------------------------------------------------------
__global__ __launch_bounds__(256) void reduce_kernel(
    const float* __restrict__ t_part,
    unsigned short* __restrict__ t_bf16)
{
    const int i  = blockIdx.x * 256 + threadIdx.x;   // over BATCH*KPAD
    const int b  = i / KPAD, rr = i % KPAD;
    float s = 0.f;
    if (rr < RTOT) {
#pragma unroll
        for (int k = 0; k < KSPLIT; ++k)
            s += t_part[((size_t)k * BATCH + b) * RTOT + rr];
    }
    t_bf16[i] = (rr < RTOT) ? (unsigned short)f2bf(s) : (unsigned short)0;
}

// ---------------------------------------------------------------------------
// Phase B: out = relu(Ucat @ t). UNCHANGED from the passing round-10 version.
// Per block 128(M) x 128(N), K = 96 (3 steps); aligned ds_read_b128 frags.
// ---------------------------------------------------------------------------
__global__ __launch_bounds__(256) void phaseB_kernel(
    const unsigned short* __restrict__ t_bf16,
    const float* __restrict__ U,
    const float* __restrict__ Ur,
    float* __restrict__ out)
{
    __shared__ __align__(16) unsigned short sU[128][104];  // [m][k]
    __shared__ __align__(16) unsigned short sT[128][104];  // [n][k]
    const int tid  = threadIdx.x;
    const int lane = tid & 63;
    const int wv   = tid >> 6;
    const int ln15 = lane & 15;
    const int g    = lane >> 4;
    const int b0   = blockIdx.x * 128;   // batch offset
    const int m0   = blockIdx.y * 128;   // out-row offset

    {
        int m = tid >> 1, h = tid & 1;
        const float* src = U + (size_t)(m0 + m) * RANK + h * 32;
#pragma unroll
        for (int c = 0; c < 8; ++c) {
            float4 v = *(const float4*)(src + c * 4);
            union { unsigned short us[4]; uint2 u2; } p;
            p.us[0] = (unsigned short)f2bf(v.x);
            p.us[1] = (unsigned short)f2bf(v.y);
            p.us[2] = (unsigned short)f2bf(v.z);
            p.us[3] = (unsigned short)f2bf(v.w);
            *(uint2*)&sU[m][h * 32 + c * 4] = p.u2;
        }
    }
    if (tid < 128) {
        int m = tid;
        float4 v = *(const float4*)(Ur + (size_t)(m0 + m) * RES_RANK);
        union { unsigned short us[4]; uint2 u2; } p;
        p.us[0] = (unsigned short)f2bf(v.x);
        p.us[1] = (unsigned short)f2bf(v.y);
        p.us[2] = (unsigned short)f2bf(v.z);
        p.us[3] = (unsigned short)f2bf(v.w);
        *(uint2*)&sU[m][64] = p.u2;
        uint2 z{0, 0};
#pragma unroll
        for (int c = 0; c < 7; ++c)
            *(uint2*)&sU[m][68 + c * 4] = z;
    }
    {
        int n = tid >> 1, c6 = (tid & 1) * 6;
        const unsigned short* src = t_bf16 + (size_t)(b0 + n) * KPAD + c6 * 8;
#pragma unroll
        for (int i = 0; i < 6; ++i) {
            uint4 v = *(const uint4*)(src + i * 8);
            *(uint4*)&sT[n][(c6 + i) * 8] = v;
        }
    }
    __syncthreads();

    f32x4 acc[2][8];
#pragma unroll
    for (int q = 0; q < 2; ++q)
#pragma unroll
        for (int nt = 0; nt < 8; ++nt)
            acc[q][nt] = (f32x4)0.0f;

#pragma unroll
    for (int ks = 0; ks < 3; ++ks) {
        bf16x8 a[2], b[8];
#pragma unroll
        for (int q = 0; q < 2; ++q) {
            int m = (wv * 2 + q) * 16 + ln15;
            a[q] = *(const bf16x8*)&sU[m][ks * 32 + g * 8];
        }
#pragma unroll
        for (int nt = 0; nt < 8; ++nt) {
            int n = nt * 16 + ln15;
            b[nt] = *(const bf16x8*)&sT[n][ks * 32 + g * 8];
        }
#pragma unroll
        for (int q = 0; q < 2; ++q)
#pragma unroll
            for (int nt = 0; nt < 8; ++nt)
                acc[q][nt] = __builtin_amdgcn_mfma_f32_16x16x32_bf16(
                    a[q], b[nt], acc[q][nt], 0, 0, 0);
    }

#pragma unroll
    for (int q = 0; q < 2; ++q)
#pragma unroll
        for (int nt = 0; nt < 8; ++nt)
#pragma unroll
            for (int r = 0; r < 4; ++r) {
                int row = m0 + (wv * 2 + q) * 16 + g * 4 + r;
                int col = b0 + nt * 16 + ln15;
                out[(size_t)row * BATCH + col] = fmaxf(acc[q][nt][r], 0.0f);
            }
}

// ---------------------------------------------------------------------------
extern "C" void kernel_launch(void* const* d_in, const int* in_sizes, int n_in,
                              void* d_out, int out_size, void* d_ws, size_t ws_size,
                              hipStream_t stream)
{
    const float* x  = (const float*)d_in[0];   // (N_IN, BATCH)
    const float* U  = (const float*)d_in[1];   // (N_OUT, RANK)
    const float* V  = (const float*)d_in[2];   // (N_IN, RANK)
    const float* Ur = (const float*)d_in[3];   // (N_OUT, RES_RANK)
    const float* Vr = (const float*)d_in[4];   // (N_IN, RES_RANK)
    float* out = (float*)d_out;                // (N_OUT, BATCH)

    // Workspace: t_part [KSPLIT][BATCH][RTOT] f32 (35.7 MB) + t_bf16 [BATCH][KPAD] (1.5 MB)
    float* t_part = (float*)d_ws;
    unsigned short* t_bf16 =
        (unsigned short*)((char*)d_ws + (size_t)KSPLIT * BATCH * RTOT * 4);

    phaseA_kernel<<<dim3(BATCH / 128, KSPLIT), 256, 0, stream>>>(x, V, Vr, t_part);
    reduce_kernel<<<dim3((BATCH * KPAD) / 256), 256, 0, stream>>>(t_part, t_bf16);
    phaseB_kernel<<<dim3(BATCH / 128, N_OUT / 128), 256, 0, stream>>>(t_bf16, U, Ur, out);
}